// Round 3
// baseline (1028.435 us; speedup 1.0000x reference)
//
#include <hip/hip_runtime.h>
#include <math.h>

// EnvelopeAR: e_t = (1-a_t) x_t + a_t e_{t-1},  a_t = s*aa + (1-s)*ar,
//             s = sigmoid(K (x_t - e_prev)), K = 50, fs = 48000.
// Chunk-parallel with warm-up (contraction tau <= 5040 samples).
// R3: W=22528, L=512 (2 waves/CU); global_load_lds double-buffer staging
// with counted vmcnt(32) so loads stay in flight across the compute block.

#define ENV_FS 48000.0f
#define ENV_A  72.13475204444817f   /* K * log2(e), K = 50 */
#define ENV_W  22528                /* warm-up steps (mult of 64) */
#define ENV_L  512                  /* output chunk length (mult of 64) */
#define ENV_SB 32                   /* super-block steps; vmcnt(32) literal below */

typedef const __attribute__((address_space(1))) unsigned int* env_gp;
typedef __attribute__((address_space(3))) unsigned int* env_lp;

static __device__ __forceinline__ float env_step(float e, float xt, float aa, float ar) {
    float w   = __builtin_fmaf(ENV_A, e, -ENV_A * xt);   // chain 1 (-A*x off-chain)
    float u   = __builtin_amdgcn_exp2f(w);               // chain 2
    float den = u + 1.0f;                                // chain 3
    float num = __builtin_fmaf(ar, u, aa);               // off-chain
    float d   = e - xt;                                  // off-chain
    float g   = num * d;                                 // overlaps rcp
    float r   = __builtin_amdgcn_rcpf(den);              // chain 4
    return __builtin_fmaf(g, r, xt);                     // chain 5
}

// ---------- transpose x[b][t] -> xT[t][b], 64x64 LDS tiles ----------
__global__ __launch_bounds__(256)
void env_transpose(const float* __restrict__ in, float* __restrict__ outT,
                   int B, int T) {
    __shared__ float tile[64][65];
    const int tb = blockIdx.x * 64;
    const int bb = blockIdx.y * 64;
    const int tx = threadIdx.x & 63;
    const int ty = threadIdx.x >> 6;
    #pragma unroll
    for (int i = ty; i < 64; i += 4)
        tile[i][tx] = in[(size_t)(bb + i) * T + tb + tx];
    __syncthreads();
    #pragma unroll
    for (int i = ty; i < 64; i += 4)
        outT[(size_t)(tb + i) * B + bb + tx] = tile[tx][i];
}

// ---------- chunk-parallel scan, LDS-staged ----------
__global__ __launch_bounds__(64, 1)
void env_compute_lds(const float* __restrict__ xT,   // [T][B]
                     const float* __restrict__ tau_a,
                     const float* __restrict__ tau_r,
                     float* __restrict__ out,        // [B][T]
                     int B, int T) {
    __shared__ float lds[2][ENV_SB][64];
    const int lane = threadIdx.x;
    const int g = blockIdx.x * 64 + lane;
    const int b = g % B;            // 64 consecutive rows per wave (B%64==0)
    const int c = g / B;            // chunk index, wave-uniform

    const int out_start = c * ENV_L;
    if (out_start >= T) return;
    int t0 = out_start - ENV_W; if (t0 < 0) t0 = 0;   // clamped chunks exact
    const int tend = out_start + ENV_L;               // T % ENV_L == 0 on fast path

    const float aa = expf(-1.0f / (tau_a[b] * ENV_FS));
    const float ar = expf(-1.0f / (tau_r[b] * ENV_FS));

    float4* __restrict__ o4 = (float4*)(out + (size_t)b * (size_t)T);
    float e = 0.0f;
    const int nsb = (tend - t0) / ENV_SB;   // t0, tend multiples of 32

#define ENV_STAGE(bufidx, tt) do { \
        const float* _g = xT + (size_t)(tt) * (size_t)B + (size_t)b; \
        _Pragma("unroll") \
        for (int _i = 0; _i < ENV_SB; ++_i) \
            __builtin_amdgcn_global_load_lds((env_gp)(_g + (size_t)_i * (size_t)B), \
                                             (env_lp)&lds[bufidx][_i][0], 4, 0, 0); \
    } while (0)

#define ENV_COMP(bufidx, tt) do { \
        const bool _st = ((tt) >= out_start);  /* wave-uniform */ \
        _Pragma("unroll") \
        for (int _j = 0; _j < ENV_SB / 4; ++_j) { \
            float4 _o; \
            _o.x = e = env_step(e, lds[bufidx][4*_j+0][lane], aa, ar); \
            _o.y = e = env_step(e, lds[bufidx][4*_j+1][lane], aa, ar); \
            _o.z = e = env_step(e, lds[bufidx][4*_j+2][lane], aa, ar); \
            _o.w = e = env_step(e, lds[bufidx][4*_j+3][lane], aa, ar); \
            if (_st) o4[((tt) >> 2) + _j] = _o; \
        } \
    } while (0)

    int t = t0;
    ENV_STAGE(0, t);
    for (int k = 0; k < nsb; ++k, t += ENV_SB) {
        const int cur = k & 1;
        if (k + 1 < nsb) {
            ENV_STAGE(cur ^ 1, t + ENV_SB);                 // 32 next-buf loads in flight
            asm volatile("s_waitcnt vmcnt(32)" ::: "memory"); // drain cur-buf (+older stores)
        } else {
            asm volatile("s_waitcnt vmcnt(0)" ::: "memory");  // epilogue: drain all
        }
        ENV_COMP(cur, t);
    }
#undef ENV_STAGE
#undef ENV_COMP
}

// ---------- fallback: direct kernel, any shape ----------
__global__ __launch_bounds__(64, 1)
void env_direct(const float* __restrict__ x,
                const float* __restrict__ tau_a,
                const float* __restrict__ tau_r,
                float* __restrict__ out,
                int B, int T) {
    const int g = blockIdx.x * 64 + threadIdx.x;
    const int b = g % B;
    const int c = g / B;
    const int out_start = c * ENV_L;
    if (out_start >= T || b >= B) return;
    int t0 = out_start - ENV_W; if (t0 < 0) t0 = 0;
    int tend = out_start + ENV_L; if (tend > T) tend = T;
    const float* __restrict__ xr = x + (size_t)b * (size_t)T;
    float* __restrict__ orow     = out + (size_t)b * (size_t)T;
    const float aa = expf(-1.0f / (tau_a[b] * ENV_FS));
    const float ar = expf(-1.0f / (tau_r[b] * ENV_FS));
    float e = 0.0f;
    for (int t = t0; t < tend; ++t) {
        e = env_step(e, xr[t], aa, ar);
        if (t >= out_start) orow[t] = e;
    }
}

extern "C" void kernel_launch(void* const* d_in, const int* in_sizes, int n_in,
                              void* d_out, int out_size, void* d_ws, size_t ws_size,
                              hipStream_t stream) {
    const float* x     = (const float*)d_in[0];
    const float* tau_a = (const float*)d_in[1];
    const float* tau_r = (const float*)d_in[2];
    float* out         = (float*)d_out;

    const int B = in_sizes[1];              // 256
    const int T = in_sizes[0] / B;          // 65536

    const int C = (T + ENV_L - 1) / ENV_L;  // chunks per row (128)
    const int total = B * C;                // 32768 threads

    const bool fast = (ws_size >= (size_t)B * (size_t)T * 4) &&
                      (B % 64 == 0) && (T % 64 == 0) && (T % ENV_L == 0);
    if (fast) {
        float* xT = (float*)d_ws;
        dim3 tgrid(T / 64, B / 64);
        env_transpose<<<tgrid, 256, 0, stream>>>(x, xT, B, T);
        env_compute_lds<<<total / 64, 64, 0, stream>>>(xT, tau_a, tau_r, out, B, T);
    } else {
        env_direct<<<(total + 63) / 64, 64, 0, stream>>>(x, tau_a, tau_r, out, B, T);
    }
}

// Round 5
// 731.853 us; speedup vs baseline: 1.4052x; 1.4052x over previous
//
#include <hip/hip_runtime.h>
#include <math.h>

// EnvelopeAR: e_t = (1-a_t) x_t + a_t e_{t-1},  a_t = s*aa + (1-s)*ar,
//             s = sigmoid(K (x_t - e_prev)), K = 50, fs = 48000.
// Chunk-parallel with warm-up (contraction time-const <= 5040 samples).
// R5: packed transpose xP[t/4][b]; PLAIN C++ register double-buffer
// (R4's inline-asm loads caused a GPU memory fault); sched_barrier(0)
// pins prefetch issue ahead of compute; chain re-associated so only
// den->rcp->fma follow exp2 on the critical path.

#define ENV_FS 48000.0f
#define ENV_A  72.13475204444817f   /* K * log2(e), K = 50 */
#define ENV_W  22528                /* warm-up steps (mult of 64) */
#define ENV_L  512                  /* output chunk length (mult of 64) */
#define ENV_SB 32                   /* steps per block = 8 float4 loads */

// e' = x + alpha*(e-x), alpha = ar + (aa-ar)*s, s = 1/(1+u), u = exp(K(e-x))
//    = base + c*r:  base = fma(ar,d,x), c = (aa-ar)*d, d = e-x  (all off-chain)
static __device__ __forceinline__ float env_step(float e, float xt, float nAx,
                                                 float ar, float m) {
    float w    = __builtin_fmaf(ENV_A, e, nAx);   // chain 1
    float u    = __builtin_amdgcn_exp2f(w);       // chain 2
    float den  = u + 1.0f;                        // chain 3
    float r    = __builtin_amdgcn_rcpf(den);      // chain 4
    float d    = e - xt;                          // off-chain (forks at e)
    float base = __builtin_fmaf(ar, d, xt);       // off-chain
    float c    = m * d;                           // off-chain
    return __builtin_fmaf(c, r, base);            // chain 5
}

// ---------- transpose+pack x[b][t] -> xP[t/4][b] (float4 over t) ----------
__global__ __launch_bounds__(256)
void env_transpose_pack(const float* __restrict__ in, float4* __restrict__ outP,
                        int B, int T) {
    __shared__ float tile[64][65];
    const int tb = blockIdx.x * 64;   // t tile base
    const int bb = blockIdx.y * 64;   // b tile base
    const int tx = threadIdx.x & 63;
    const int ty = threadIdx.x >> 6;  // 0..3
    #pragma unroll
    for (int i = ty; i < 64; i += 4)                      // coalesced along t
        tile[i][tx] = in[(size_t)(bb + i) * T + tb + tx]; // tile[b'][t']
    __syncthreads();
    #pragma unroll
    for (int j = ty; j < 16; j += 4) {                    // 4 t-steps per float4
        float4 v;
        v.x = tile[tx][4 * j + 0];
        v.y = tile[tx][4 * j + 1];
        v.z = tile[tx][4 * j + 2];
        v.w = tile[tx][4 * j + 3];
        outP[(size_t)((tb >> 2) + j) * B + bb + tx] = v;  // coalesced along b
    }
}

// ---------- chunk-parallel scan, plain register double-buffer ----------
__global__ __launch_bounds__(64, 1)
void env_compute_reg(const float4* __restrict__ xP,   // [T/4][B]
                     const float* __restrict__ tau_a,
                     const float* __restrict__ tau_r,
                     float* __restrict__ out,         // [B][T]
                     int B, int T) {
    const int lane = threadIdx.x;
    const int g = blockIdx.x * 64 + lane;
    const int b = g % B;            // 64 consecutive rows per wave (B%64==0)
    const int c = g / B;            // chunk index, wave-uniform

    const int out_start = c * ENV_L;
    if (out_start >= T) return;
    int t0 = out_start - ENV_W; if (t0 < 0) t0 = 0;   // clamped chunks exact
    const int tend = out_start + ENV_L;               // T % ENV_L == 0 on fast path

    const float aa = expf(-1.0f / (tau_a[b] * ENV_FS));
    const float ar = expf(-1.0f / (tau_r[b] * ENV_FS));
    const float m  = aa - ar;

    float4* __restrict__ o4 = (float4*)(out + (size_t)b * (size_t)T);
    float e = 0.0f;
    const int nblk = (tend - t0) >> 5;   // t0, tend multiples of 32
    float4 bufA[8], bufB[8];             // static indexing only (rule #20)

#define ENV_LOAD8(buf, tt) do { \
        const float4* __restrict__ _p = xP + (size_t)((tt) >> 2) * (size_t)B + (size_t)b; \
        _Pragma("unroll") \
        for (int _j = 0; _j < 8; ++_j) (buf)[_j] = _p[(size_t)_j * (size_t)B]; \
    } while (0)

#define ENV_COMP(buf, tt) do { \
        const bool _st = ((tt) >= out_start);  /* wave-uniform */ \
        _Pragma("unroll") \
        for (int _j = 0; _j < 8; ++_j) { \
            const float4 _xi = (buf)[_j]; \
            const float _n0 = -ENV_A * _xi.x, _n1 = -ENV_A * _xi.y; \
            const float _n2 = -ENV_A * _xi.z, _n3 = -ENV_A * _xi.w; \
            float4 _o; \
            _o.x = e = env_step(e, _xi.x, _n0, ar, m); \
            _o.y = e = env_step(e, _xi.y, _n1, ar, m); \
            _o.z = e = env_step(e, _xi.z, _n2, ar, m); \
            _o.w = e = env_step(e, _xi.w, _n3, ar, m); \
            if (_st) o4[((tt) >> 2) + _j] = _o; \
        } \
    } while (0)

    int t = t0, k = 0;
    if (nblk > 0) {
        ENV_LOAD8(bufA, t);
        for (;;) {
            if (k + 1 < nblk) ENV_LOAD8(bufB, t + ENV_SB);   // prefetch next block
            __builtin_amdgcn_sched_barrier(0);               // pin issue before compute
            ENV_COMP(bufA, t);
            ++k; t += ENV_SB;
            if (k >= nblk) break;
            if (k + 1 < nblk) ENV_LOAD8(bufA, t + ENV_SB);
            __builtin_amdgcn_sched_barrier(0);
            ENV_COMP(bufB, t);
            ++k; t += ENV_SB;
            if (k >= nblk) break;
        }
    }
#undef ENV_LOAD8
#undef ENV_COMP
}

// ---------- fallback: direct kernel, any shape ----------
__global__ __launch_bounds__(64, 1)
void env_direct(const float* __restrict__ x,
                const float* __restrict__ tau_a,
                const float* __restrict__ tau_r,
                float* __restrict__ out,
                int B, int T) {
    const int g = blockIdx.x * 64 + threadIdx.x;
    const int b = g % B;
    const int c = g / B;
    const int out_start = c * ENV_L;
    if (out_start >= T || b >= B) return;
    int t0 = out_start - ENV_W; if (t0 < 0) t0 = 0;
    int tend = out_start + ENV_L; if (tend > T) tend = T;
    const float* __restrict__ xr = x + (size_t)b * (size_t)T;
    float* __restrict__ orow     = out + (size_t)b * (size_t)T;
    const float aa = expf(-1.0f / (tau_a[b] * ENV_FS));
    const float ar = expf(-1.0f / (tau_r[b] * ENV_FS));
    const float m  = aa - ar;
    float e = 0.0f;
    for (int t = t0; t < tend; ++t) {
        const float xt = xr[t];
        e = env_step(e, xt, -ENV_A * xt, ar, m);
        if (t >= out_start) orow[t] = e;
    }
}

extern "C" void kernel_launch(void* const* d_in, const int* in_sizes, int n_in,
                              void* d_out, int out_size, void* d_ws, size_t ws_size,
                              hipStream_t stream) {
    const float* x     = (const float*)d_in[0];
    const float* tau_a = (const float*)d_in[1];
    const float* tau_r = (const float*)d_in[2];
    float* out         = (float*)d_out;

    const int B = in_sizes[1];              // 256
    const int T = in_sizes[0] / B;          // 65536

    const int C = (T + ENV_L - 1) / ENV_L;  // chunks per row (128)
    const int total = B * C;                // 32768 threads

    const bool fast = (ws_size >= (size_t)B * (size_t)T * 4) &&
                      (B % 64 == 0) && (T % 64 == 0) && (T % ENV_L == 0);
    if (fast) {
        float4* xP = (float4*)d_ws;
        dim3 tgrid(T / 64, B / 64);
        env_transpose_pack<<<tgrid, 256, 0, stream>>>(x, xP, B, T);
        env_compute_reg<<<total / 64, 64, 0, stream>>>(xP, tau_a, tau_r, out, B, T);
    } else {
        env_direct<<<(total + 63) / 64, 64, 0, stream>>>(x, tau_a, tau_r, out, B, T);
    }
}